// Round 8
// baseline (31.082 us; speedup 1.0000x reference)
//
#include <hip/hip_runtime.h>
#include <math.h>

// MoE router: x [16384, 2048] f32, gate_w [8, 2048] f32
// outputs (concatenated f32): weights [16384,2] | mask [8,2,16384] | logits [16384,8]
//
// Column-slice structure: 8 waves/block, wave wv owns cols [wv*256, wv*256+256).
// Gates held in 32 VGPRs (loaded once). Block reads rows fully contiguously
// (8 waves x 1KB = whole 8KB row), rows sequential -> fill-like DRAM pattern.
// Steady-state VMEM = 1 x-load per row per wave, prefetch distance 3.
// PLAIN loads (no nontemporal): x (128 MiB) is L3-resident (256 MiB) across
// graph replays -> steady-state reads come from Infinity Cache, not HBM.

constexpr int kN = 16384;
constexpr int kD = 2048;
constexpr int kE = 8;

using f4 = __attribute__((ext_vector_type(4))) float;

__global__ __launch_bounds__(512, 4)
void moe_router_kernel(const float* __restrict__ x,
                       const float* __restrict__ gw,
                       float* __restrict__ out)
{
    __shared__ float part[2][512];        // [buf][wv*64 + r*8 + e], 4 KiB

    const int tid  = threadIdx.x;
    const int lane = tid & 63;
    const int wv   = tid >> 6;                     // 0..7 column-slice owner
    const int col  = wv * 256 + lane * 4;          // this lane's 4 columns
    const int rowbase = blockIdx.x * 32;           // 32 rows per block

    const float* xc = x + col;

    // gate fragment, resident for the whole kernel (32 VGPRs)
    f4 g[8];
#pragma unroll
    for (int e = 0; e < 8; ++e)
        g[e] = *reinterpret_cast<const f4*>(gw + e * kD + col);

    float* out_w = out;                            // [N, 2]
    float* out_m = out + 2 * kN;                   // [E, 2, N]
    float* out_l = out + 2 * kN + 2 * kE * kN;     // [N, 8]

    // rolling x buffer: 4 slots, prefetch distance 3 (3 KB/wave in flight,
    // never drained: barriers below wait lgkmcnt only, not vmcnt)
    f4 xb[4];
#pragma unroll
    for (int p = 0; p < 3; ++p)
        xb[p] = *reinterpret_cast<const f4*>(xc + (long)(rowbase + p) * kD);

    float acc[8][8];
    const int b0 = lane & 1, b1 = (lane >> 1) & 1, b2 = (lane >> 2) & 1;

#pragma unroll 1
    for (int gidx = 0; gidx < 4; ++gidx) {
        const int r0 = rowbase + gidx * 8;

        // ---- 8 rows: 1 VMEM + 32 FMA each; acc[r][e] starts with a mul ----
#pragma unroll
        for (int r = 0; r < 8; ++r) {
            int prow = r0 + r + 3;                     // next prefetch row
            prow = prow > kN - 1 ? kN - 1 : prow;      // clamp (last block tail)
            xb[(r + 3) & 3] = *reinterpret_cast<const f4*>(xc + (long)prow * kD);
            const f4 xv = xb[r & 3];
#pragma unroll
            for (int e = 0; e < 8; ++e) {
                float t = xv.x * g[e].x;               // overwrites old acc
                t = fmaf(xv.y, g[e].y, t);
                t = fmaf(xv.z, g[e].z, t);
                acc[r][e] = fmaf(xv.w, g[e].w, t);
            }
        }

        // ---- in-place in-wave fold: 80 shuffles; afterwards acc[0][e] =
        // slice-partial logit of row r0+(lane&7), expert e ----
#pragma unroll
        for (int j = 0; j < 4; ++j)
#pragma unroll
            for (int e = 0; e < 8; ++e) {
                const float mine  = b0 ? acc[2 * j + 1][e] : acc[2 * j][e];
                const float other = b0 ? acc[2 * j][e]     : acc[2 * j + 1][e];
                acc[j][e] = mine + __shfl_xor(other, 1);
            }
#pragma unroll
        for (int k = 0; k < 2; ++k)
#pragma unroll
            for (int e = 0; e < 8; ++e) {
                const float mine  = b1 ? acc[2 * k + 1][e] : acc[2 * k][e];
                const float other = b1 ? acc[2 * k][e]     : acc[2 * k + 1][e];
                acc[k][e] = mine + __shfl_xor(other, 2);
            }
#pragma unroll
        for (int e = 0; e < 8; ++e) {
            const float mine  = b2 ? acc[1][e] : acc[0][e];
            const float other = b2 ? acc[0][e] : acc[1][e];
            float v = mine + __shfl_xor(other, 4);
            v += __shfl_xor(v, 8);
            v += __shfl_xor(v, 16);
            v += __shfl_xor(v, 32);
            acc[0][e] = v;
        }

        // ---- scatter this wave's partials: lane -> (r=lane&7, e=lane>>3) ----
        {
            const int er = lane >> 3;
            float v = acc[0][0];
#pragma unroll
            for (int e = 1; e < 8; ++e) v = (er == e) ? acc[0][e] : v;
            part[gidx & 1][wv * 64 + (lane & 7) * 8 + er] = v;
        }
        asm volatile("s_waitcnt lgkmcnt(0)" ::: "memory");
        __builtin_amdgcn_sched_barrier(0);
        __builtin_amdgcn_s_barrier();               // no vmcnt drain: x prefetch
        __builtin_amdgcn_sched_barrier(0);          // stays in flight

        // ---- epilogue (one wave per group, rotating): rows r0..r0+7 ----
        if (wv == gidx) {
            const int r = lane & 7, c = lane >> 3;  // lane -> (row, expert)
            const float* pb = &part[gidx & 1][0];
            float L = 0.f;
#pragma unroll
            for (int w = 0; w < 8; ++w)
                L += pb[w * 64 + r * 8 + c];        // logit[r0+r][c]

            float le[8];                            // gather row's 8 logits
#pragma unroll
            for (int e = 0; e < 8; ++e)
                le[e] = __shfl(L, r + 8 * e);

            int s0 = 0; float v0 = le[0];
#pragma unroll
            for (int e = 1; e < 8; ++e)
                if (le[e] > v0) { v0 = le[e]; s0 = e; }
            int s1 = 0; float v1 = -3.4e38f;
#pragma unroll
            for (int e = 0; e < 8; ++e) {
                const bool t = (e != s0) && (le[e] > v1);
                v1 = t ? le[e] : v1;
                s1 = t ? e : s1;
            }
            const float d  = expf(v1 - v0);         // <= 1
            const float w0 = 1.0f / (1.0f + d);     // p0/(p0+p1)
            const float w1 = d * w0;

            out_l[(long)(r0 + r) * 8 + c] = L;
            out_m[(long)c * (2 * kN) + (r0 + r)]      = (s0 == c) ? 1.0f : 0.0f;
            out_m[(long)c * (2 * kN) + kN + (r0 + r)] = (s1 == c) ? 1.0f : 0.0f;
            if (c == 0) {
                float2 wp; wp.x = w0; wp.y = w1;
                *reinterpret_cast<float2*>(out_w + (long)(r0 + r) * 2) = wp;
            }
        }
    }
}

extern "C" void kernel_launch(void* const* d_in, const int* in_sizes, int n_in,
                              void* d_out, int out_size, void* d_ws, size_t ws_size,
                              hipStream_t stream)
{
    (void)in_sizes; (void)n_in; (void)d_ws; (void)ws_size; (void)out_size;
    const float* x  = (const float*)d_in[0];
    const float* gw = (const float*)d_in[1];
    float* out = (float*)d_out;

    dim3 grid(kN / 32);   // 512 blocks x 32 rows; 2 blocks/CU
    dim3 block(512);      // 8 waves, one column slice each
    moe_router_kernel<<<grid, block, 0, stream>>>(x, gw, out);
}